// Round 4
// baseline (359.346 us; speedup 1.0000x reference)
//
#include <hip/hip_runtime.h>
#include <hip/hip_cooperative_groups.h>
#include <math.h>

namespace cg = cooperative_groups;

// Problem constants (fixed by setup_inputs)
#define B   4096
#define D   1024
#define C   10000
#define SCALE_F  30.0f
#define LAMBDA_F 0.1f
#define EPS_F    1e-6f
#define LOG2E    1.4426950408889634f
#define LN2      0.6931471805599453f
#define K2       (SCALE_F * LOG2E)     // scale folded into log2 domain
#define NEG_BIG  (-3.402823466e38f)

#define NBLK 1024      // 4 blocks/CU on 256 CUs — co-resident for cooperative launch
#define NTHR 256

// ws layout (floats): [0,NBLK) ce partials | [NBLK,2NBLK) center | [2NBLK,3NBLK) sumsq

// Combine two (max, sum) partial logsumexp states in the log2 domain.
__device__ inline void lse2_combine(float& m, float& s, float m2, float s2) {
    float mn = fmaxf(m, m2);
    s = s * exp2f(m - mn) + s2 * exp2f(m2 - mn);
    m = mn;
}

// One float4 of a CE row folded into a (m, s) log2-domain LSE state.
__device__ inline void ce_chunk(const float4* __restrict__ rowp, int i,
                                float& m, float& s) {
    float4 v = rowp[i];
    float z0 = v.x * K2, z1 = v.y * K2, z2 = v.z * K2, z3 = v.w * K2;
    float mloc = fmaxf(fmaxf(z0, z1), fmaxf(z2, z3));
    float mn = fmaxf(m, mloc);
    s = s * exp2f(m - mn)
      + exp2f(z0 - mn) + exp2f(z1 - mn) + exp2f(z2 - mn) + exp2f(z3 - mn);
    m = mn;
}

__global__ __launch_bounds__(NTHR, 4)
void mega_kernel(const float* __restrict__ outputs,
                 const float* __restrict__ anchor,
                 const float* __restrict__ negative,
                 const float* __restrict__ exemplars,
                 const int* __restrict__ labels_a,
                 const int* __restrict__ labels_n,
                 float* __restrict__ ws,
                 float* __restrict__ out) {
    const int bid = blockIdx.x;
    const int tid = threadIdx.x;
    const int wid = tid >> 6, lane = tid & 63;
    __shared__ float sm[4][4];

    // ---------- phase 1: exemplar sum-of-squares (streams exemplars -> L3) ----------
    {
        const float4* p = (const float4*)exemplars;
        const int n4 = C * D / 4;                       // 2,560,000
        float s = 0.0f;
        for (int i = bid * NTHR + tid; i < n4; i += NBLK * NTHR) {
            float4 v = p[i];
            s = fmaf(v.x, v.x, s); s = fmaf(v.y, v.y, s);
            s = fmaf(v.z, v.z, s); s = fmaf(v.w, v.w, s);
        }
        #pragma unroll
        for (int off = 1; off < 64; off <<= 1) s += __shfl_xor(s, off, 64);
        if (lane == 0) sm[wid][0] = s;
        __syncthreads();
        if (tid == 0) ws[2 * NBLK + bid] = sm[0][0] + sm[1][0] + sm[2][0] + sm[3][0];
        __syncthreads();
    }

    // ---------- phase 2: center-hinge rows (4 per block; gathers hit L3) ----------
    float cen_acc = 0.0f;                               // live on tid 0
    for (int r = 0; r < B / NBLK; ++r) {
        const int row = bid + r * NBLK;
        const int la = labels_a[row];
        const int ln = labels_n[row];

        float4 a  = ((const float4*)(anchor    + (size_t)row * D))[tid];
        float4 n  = ((const float4*)(negative  + (size_t)row * D))[tid];
        float4 ea = ((const float4*)(exemplars + (size_t)la  * D))[tid];
        float4 en = ((const float4*)(exemplars + (size_t)ln  * D))[tid];

        float s1 = fabsf(a.x - ea.x + EPS_F) + fabsf(a.y - ea.y + EPS_F)
                 + fabsf(a.z - ea.z + EPS_F) + fabsf(a.w - ea.w + EPS_F);
        float s2 = fabsf(n.x - ea.x + EPS_F) + fabsf(n.y - ea.y + EPS_F)
                 + fabsf(n.z - ea.z + EPS_F) + fabsf(n.w - ea.w + EPS_F);
        float s3 = fabsf(a.x - en.x + EPS_F) + fabsf(a.y - en.y + EPS_F)
                 + fabsf(a.z - en.z + EPS_F) + fabsf(a.w - en.w + EPS_F);
        float s4 = fabsf(n.x - en.x + EPS_F) + fabsf(n.y - en.y + EPS_F)
                 + fabsf(n.z - en.z + EPS_F) + fabsf(n.w - en.w + EPS_F);

        #pragma unroll
        for (int off = 1; off < 64; off <<= 1) {
            s1 += __shfl_xor(s1, off, 64);
            s2 += __shfl_xor(s2, off, 64);
            s3 += __shfl_xor(s3, off, 64);
            s4 += __shfl_xor(s4, off, 64);
        }
        if (lane == 0) { sm[wid][0] = s1; sm[wid][1] = s2; sm[wid][2] = s3; sm[wid][3] = s4; }
        __syncthreads();
        if (tid == 0) {
            float t1 = sm[0][0] + sm[1][0] + sm[2][0] + sm[3][0];
            float t2 = sm[0][1] + sm[1][1] + sm[2][1] + sm[3][1];
            float t3 = sm[0][2] + sm[1][2] + sm[2][2] + sm[3][2];
            float t4 = sm[0][3] + sm[1][3] + sm[2][3] + sm[3][3];
            cen_acc += fmaxf(t1 - t2, 0.0f) + fmaxf(t4 - t3, 0.0f);
        }
        __syncthreads();
    }
    if (tid == 0) ws[NBLK + bid] = cen_acc;

    // ---------- phase 3: cross-entropy rows (8 per block), log2 domain ----------
    float ce_acc = 0.0f;                                // live on tid 0
    for (int r = 0; r < 2 * B / NBLK; ++r) {
        const int row = bid + r * NBLK;
        const int lab = (row < B) ? labels_a[row] : labels_n[row - B];
        const float* rowbase = outputs + (size_t)row * C;
        const float4* rowp = (const float4*)rowbase;
        const float target = rowbase[lab];

        // two independent LSE chains to deepen the memory/exp2 pipeline
        float m0 = NEG_BIG, s0 = 0.0f, m1 = NEG_BIG, s1 = 0.0f;
        for (int i = tid; i < C / 4; i += 2 * NTHR) {
            ce_chunk(rowp, i, m0, s0);
            const int j = i + NTHR;
            if (j < C / 4) ce_chunk(rowp, j, m1, s1);
        }
        lse2_combine(m0, s0, m1, s1);

        #pragma unroll
        for (int off = 1; off < 64; off <<= 1) {
            float m2 = __shfl_xor(m0, off, 64);
            float s2 = __shfl_xor(s0, off, 64);
            lse2_combine(m0, s0, m2, s2);
        }
        if (lane == 0) { sm[wid][0] = m0; sm[wid][1] = s0; }
        __syncthreads();
        if (tid == 0) {
            float M = sm[0][0], S = sm[0][1];
            lse2_combine(M, S, sm[1][0], sm[1][1]);
            lse2_combine(M, S, sm[2][0], sm[2][1]);
            lse2_combine(M, S, sm[3][0], sm[3][1]);
            ce_acc += (M + log2f(S)) * LN2 - SCALE_F * target;
        }
        __syncthreads();
    }
    if (tid == 0) ws[bid] = ce_acc;

    // ---------- grid-wide barrier, then block 0 finalizes ----------
    __threadfence();                 // device-scope visibility of partials
    cg::this_grid().sync();

    if (bid == 0) {
        float ce = 0.0f, cen = 0.0f, sq = 0.0f;
        for (int i = tid; i < NBLK; i += NTHR) {
            ce  += ws[i];
            cen += ws[NBLK + i];
            sq  += ws[2 * NBLK + i];
        }
        #pragma unroll
        for (int off = 1; off < 64; off <<= 1) {
            ce  += __shfl_xor(ce,  off, 64);
            cen += __shfl_xor(cen, off, 64);
            sq  += __shfl_xor(sq,  off, 64);
        }
        if (lane == 0) { sm[wid][0] = ce; sm[wid][1] = cen; sm[wid][2] = sq; }
        __syncthreads();
        if (tid == 0) {
            float CE  = (sm[0][0] + sm[1][0] + sm[2][0] + sm[3][0]) * (1.0f / (2.0f * B));
            float CEN =  sm[0][1] + sm[1][1] + sm[2][1] + sm[3][1];
            float SQ  =  sm[0][2] + sm[1][2] + sm[2][2] + sm[3][2];
            float total = (SQ == 0.0f) ? CE : CE + LAMBDA_F * CEN;
            out[0] = total;
            out[1] = CE;
            out[2] = CEN;
        }
    }
}

extern "C" void kernel_launch(void* const* d_in, const int* in_sizes, int n_in,
                              void* d_out, int out_size, void* d_ws, size_t ws_size,
                              hipStream_t stream) {
    const float* anchor    = (const float*)d_in[0];
    const float* negative  = (const float*)d_in[1];
    const float* outputs   = (const float*)d_in[2];
    const int*   labels_a  = (const int*)d_in[3];
    const int*   labels_n  = (const int*)d_in[4];
    const float* exemplars = (const float*)d_in[5];
    float* out = (float*)d_out;
    float* ws  = (float*)d_ws;

    void* args[] = { (void*)&outputs, (void*)&anchor, (void*)&negative,
                     (void*)&exemplars, (void*)&labels_a, (void*)&labels_n,
                     (void*)&ws, (void*)&out };
    hipLaunchCooperativeKernel((const void*)mega_kernel,
                               dim3(NBLK), dim3(NTHR), args, 0, stream);
}

// Round 5
// 92.325 us; speedup vs baseline: 3.8922x; 3.8922x over previous
//
#include <hip/hip_runtime.h>
#include <math.h>

// Problem constants (fixed by setup_inputs)
#define B   4096
#define D   1024
#define C   10000
#define SCALE_F  30.0f
#define LAMBDA_F 0.1f
#define EPS_F    1e-6f
#define LOG2E    1.4426950408889634f
#define LN2      0.6931471805599453f
#define K2       (SCALE_F * LOG2E)     // scale folded into log2 domain
#define NEG_BIG  (-3.402823466e38f)

// Block roles, in dispatch order: sumsq streams exemplars into L3 FIRST so
// the center blocks' exemplar gathers hit L3.
#define SQ_BLOCKS 2048
#define CEN_BLOCKS B            // 4096
#define CE_BLOCKS  (2 * B)      // 8192
#define TOTAL_BLOCKS (SQ_BLOCKS + CEN_BLOCKS + CE_BLOCKS)   // 14336

// ws layout (floats):
//   [0            .. SQ_BLOCKS)              sumsq partials
//   [SQ_BLOCKS    .. SQ_BLOCKS+B)            center partials
//   [SQ_BLOCKS+B  .. SQ_BLOCKS+B+2B)         ce partials
#define SQ_OFF   0
#define CEN_OFF  SQ_BLOCKS
#define CE_OFF   (SQ_BLOCKS + B)

// Combine two (max, sum) partial logsumexp states in the log2 domain.
__device__ inline void lse2_combine(float& m, float& s, float m2, float s2) {
    float mn = fmaxf(m, m2);
    s = s * exp2f(m - mn) + s2 * exp2f(m2 - mn);
    m = mn;
}

// One float4 of a CE row folded into a (m, s) log2-domain LSE state.
__device__ inline void ce_chunk(const float4* __restrict__ rowp, int i,
                                float& m, float& s) {
    float4 v = rowp[i];
    float z0 = v.x * K2, z1 = v.y * K2, z2 = v.z * K2, z3 = v.w * K2;
    float mloc = fmaxf(fmaxf(z0, z1), fmaxf(z2, z3));
    float mn = fmaxf(m, mloc);
    s = s * exp2f(m - mn)
      + exp2f(z0 - mn) + exp2f(z1 - mn) + exp2f(z2 - mn) + exp2f(z3 - mn);
    m = mn;
}

__global__ __launch_bounds__(256) void fused_kernel(const float* __restrict__ outputs,
                                                    const float* __restrict__ anchor,
                                                    const float* __restrict__ negative,
                                                    const float* __restrict__ exemplars,
                                                    const int* __restrict__ labels_a,
                                                    const int* __restrict__ labels_n,
                                                    float* __restrict__ ws) {
    const int blk = blockIdx.x;
    const int tid = threadIdx.x;
    const int wid = tid >> 6, lane = tid & 63;

    if (blk < SQ_BLOCKS) {
        // ---------------- exemplar sum-of-squares chunk (warms L3) ----------------
        const int chunk = blk;
        const int n4 = C * D / 4;                 // 2,560,000 float4
        const float4* p = (const float4*)exemplars;
        float s = 0.0f;
        for (int i = chunk * 256 + tid; i < n4; i += SQ_BLOCKS * 256) {
            float4 v = p[i];
            s = fmaf(v.x, v.x, s); s = fmaf(v.y, v.y, s);
            s = fmaf(v.z, v.z, s); s = fmaf(v.w, v.w, s);
        }
        #pragma unroll
        for (int off = 1; off < 64; off <<= 1) s += __shfl_xor(s, off, 64);

        __shared__ float smq[4];
        if (lane == 0) smq[wid] = s;
        __syncthreads();
        if (tid == 0) ws[SQ_OFF + chunk] = smq[0] + smq[1] + smq[2] + smq[3];
    } else if (blk < SQ_BLOCKS + CEN_BLOCKS) {
        // ---------------- center-hinge row ----------------
        const int row = blk - SQ_BLOCKS;
        const int la = labels_a[row];
        const int ln = labels_n[row];

        float4 a  = ((const float4*)(anchor    + (size_t)row * D))[tid];
        float4 n  = ((const float4*)(negative  + (size_t)row * D))[tid];
        float4 ea = ((const float4*)(exemplars + (size_t)la  * D))[tid];
        float4 en = ((const float4*)(exemplars + (size_t)ln  * D))[tid];

        // s1=d_ref1(a,ea) s2=d_neg1(n,ea) s3=d_ref2(a,en) s4=d_neg2(n,en)
        float s1 = fabsf(a.x - ea.x + EPS_F) + fabsf(a.y - ea.y + EPS_F)
                 + fabsf(a.z - ea.z + EPS_F) + fabsf(a.w - ea.w + EPS_F);
        float s2 = fabsf(n.x - ea.x + EPS_F) + fabsf(n.y - ea.y + EPS_F)
                 + fabsf(n.z - ea.z + EPS_F) + fabsf(n.w - ea.w + EPS_F);
        float s3 = fabsf(a.x - en.x + EPS_F) + fabsf(a.y - en.y + EPS_F)
                 + fabsf(a.z - en.z + EPS_F) + fabsf(a.w - en.w + EPS_F);
        float s4 = fabsf(n.x - en.x + EPS_F) + fabsf(n.y - en.y + EPS_F)
                 + fabsf(n.z - en.z + EPS_F) + fabsf(n.w - en.w + EPS_F);

        #pragma unroll
        for (int off = 1; off < 64; off <<= 1) {
            s1 += __shfl_xor(s1, off, 64);
            s2 += __shfl_xor(s2, off, 64);
            s3 += __shfl_xor(s3, off, 64);
            s4 += __shfl_xor(s4, off, 64);
        }

        __shared__ float sm[4][4];
        if (lane == 0) { sm[wid][0] = s1; sm[wid][1] = s2; sm[wid][2] = s3; sm[wid][3] = s4; }
        __syncthreads();
        if (tid == 0) {
            float t1 = sm[0][0] + sm[1][0] + sm[2][0] + sm[3][0];
            float t2 = sm[0][1] + sm[1][1] + sm[2][1] + sm[3][1];
            float t3 = sm[0][2] + sm[1][2] + sm[2][2] + sm[3][2];
            float t4 = sm[0][3] + sm[1][3] + sm[2][3] + sm[3][3];
            ws[CEN_OFF + row] = fmaxf(t1 - t2, 0.0f) + fmaxf(t4 - t3, 0.0f);
        }
    } else {
        // ---------------- cross-entropy row, log2 domain, 2 ILP chains ----------
        const int row = blk - (SQ_BLOCKS + CEN_BLOCKS);
        const int lab = (row < B) ? labels_a[row] : labels_n[row - B];
        const float* rowbase = outputs + (size_t)row * C;
        const float4* rowp = (const float4*)rowbase;
        const float target = rowbase[lab];   // broadcast load

        float m0 = NEG_BIG, s0 = 0.0f, m1 = NEG_BIG, s1 = 0.0f;
        for (int i = tid; i < C / 4; i += 512) {
            ce_chunk(rowp, i, m0, s0);
            const int j = i + 256;
            if (j < C / 4) ce_chunk(rowp, j, m1, s1);
        }
        lse2_combine(m0, s0, m1, s1);

        #pragma unroll
        for (int off = 1; off < 64; off <<= 1) {
            float m2 = __shfl_xor(m0, off, 64);
            float s2 = __shfl_xor(s0, off, 64);
            lse2_combine(m0, s0, m2, s2);
        }

        __shared__ float sm_m[4], sm_s[4];
        if (lane == 0) { sm_m[wid] = m0; sm_s[wid] = s0; }
        __syncthreads();
        if (tid == 0) {
            float M = sm_m[0], S = sm_s[0];
            lse2_combine(M, S, sm_m[1], sm_s[1]);
            lse2_combine(M, S, sm_m[2], sm_s[2]);
            lse2_combine(M, S, sm_m[3], sm_s[3]);
            ws[CE_OFF + row] = (M + log2f(S)) * LN2 - SCALE_F * target;
        }
    }
}

// ---------------------------------------------------------------------------
// Finalize — reduce all partials, write d_out[3].
// ---------------------------------------------------------------------------
__global__ __launch_bounds__(256) void finalize_kernel(const float* __restrict__ ws,
                                                       float* __restrict__ out) {
    const int tid = threadIdx.x;
    float ce = 0.0f, cen = 0.0f, sq = 0.0f;
    for (int i = tid; i < CE_BLOCKS; i += 256)  ce  += ws[CE_OFF  + i];
    for (int i = tid; i < B; i += 256)          cen += ws[CEN_OFF + i];
    for (int i = tid; i < SQ_BLOCKS; i += 256)  sq  += ws[SQ_OFF  + i];

    #pragma unroll
    for (int off = 1; off < 64; off <<= 1) {
        ce  += __shfl_xor(ce,  off, 64);
        cen += __shfl_xor(cen, off, 64);
        sq  += __shfl_xor(sq,  off, 64);
    }

    __shared__ float sm[4][3];
    const int wid = tid >> 6, lane = tid & 63;
    if (lane == 0) { sm[wid][0] = ce; sm[wid][1] = cen; sm[wid][2] = sq; }
    __syncthreads();
    if (tid == 0) {
        float CE  = (sm[0][0] + sm[1][0] + sm[2][0] + sm[3][0]) * (1.0f / (2.0f * B));
        float CEN =  sm[0][1] + sm[1][1] + sm[2][1] + sm[3][1];
        float SQ  =  sm[0][2] + sm[1][2] + sm[2][2] + sm[3][2];
        float total = (SQ == 0.0f) ? CE : CE + LAMBDA_F * CEN;
        out[0] = total;
        out[1] = CE;
        out[2] = CEN;
    }
}

extern "C" void kernel_launch(void* const* d_in, const int* in_sizes, int n_in,
                              void* d_out, int out_size, void* d_ws, size_t ws_size,
                              hipStream_t stream) {
    const float* anchor    = (const float*)d_in[0];
    const float* negative  = (const float*)d_in[1];
    const float* outputs   = (const float*)d_in[2];
    const int*   labels_a  = (const int*)d_in[3];
    const int*   labels_n  = (const int*)d_in[4];
    const float* exemplars = (const float*)d_in[5];
    float* out = (float*)d_out;
    float* ws  = (float*)d_ws;

    fused_kernel<<<TOTAL_BLOCKS, 256, 0, stream>>>(outputs, anchor, negative,
                                                   exemplars, labels_a, labels_n, ws);
    finalize_kernel<<<1, 256, 0, stream>>>(ws, out);
}

// Round 7
// 84.247 us; speedup vs baseline: 4.2654x; 1.0959x over previous
//
#include <hip/hip_runtime.h>
#include <math.h>

// Problem constants (fixed by setup_inputs)
#define B   4096
#define D   1024
#define C   10000
#define SCALE_F  30.0f
#define LAMBDA_F 0.1f
#define EPS_F    1e-6f
#define LOG2E    1.4426950408889634f
#define LN2      0.6931471805599453f
#define K2       (SCALE_F * LOG2E)     // scale folded into log2 domain
#define NEG_BIG  (-3.402823466e38f)

typedef float floatx4 __attribute__((ext_vector_type(4)));  // nt-load-compatible

// Block roles in dispatch order (round-3 measured-best order):
//   [0, 2B)            : cross-entropy rows
//   [2B, 3B)           : center-hinge rows
//   [3B, 3B+SQ_BLOCKS) : exemplar sum-of-squares chunks
#define CE_BLOCKS (2 * B)       // 8192
#define CEN_BLOCKS B            // 4096
#define SQ_BLOCKS 2048
#define TOTAL_BLOCKS (CE_BLOCKS + CEN_BLOCKS + SQ_BLOCKS)   // 14336

// ws layout (floats):
#define CE_OFF   0
#define CEN_OFF  (2 * B)
#define SQ_OFF   (3 * B)

// Combine two (max, sum) partial logsumexp states in the log2 domain.
__device__ inline void lse2_combine(float& m, float& s, float m2, float s2) {
    float mn = fmaxf(m, m2);
    s = s * exp2f(m - mn) + s2 * exp2f(m2 - mn);
    m = mn;
}

__global__ __launch_bounds__(256) void fused_kernel(const float* __restrict__ outputs,
                                                    const float* __restrict__ anchor,
                                                    const float* __restrict__ negative,
                                                    const float* __restrict__ exemplars,
                                                    const int* __restrict__ labels_a,
                                                    const int* __restrict__ labels_n,
                                                    float* __restrict__ ws) {
    const int blk = blockIdx.x;
    const int tid = threadIdx.x;
    const int wid = tid >> 6, lane = tid & 63;

    if (blk < CE_BLOCKS) {
        // ---------------- cross-entropy row (log2 domain) ----------------
        const int row = blk;
        const int lab = (row < B) ? labels_a[row] : labels_n[row - B];
        const float* rowbase = outputs + (size_t)row * C;
        const floatx4* rowp = (const floatx4*)rowbase;
        const float target = rowbase[lab];   // broadcast load

        float m = NEG_BIG, s = 0.0f;
        #pragma unroll 2
        for (int i = tid; i < C / 4; i += 256) {
            floatx4 v = __builtin_nontemporal_load(&rowp[i]);   // single-touch stream
            float z0 = v.x * K2, z1 = v.y * K2, z2 = v.z * K2, z3 = v.w * K2;
            float mloc = fmaxf(fmaxf(z0, z1), fmaxf(z2, z3));
            float mn = fmaxf(m, mloc);
            float sc = exp2f(m - mn);
            float e = exp2f(z0 - mn) + exp2f(z1 - mn)
                    + exp2f(z2 - mn) + exp2f(z3 - mn);
            s = fmaf(s, sc, e);
            m = mn;
        }

        #pragma unroll
        for (int off = 1; off < 64; off <<= 1) {
            float m2 = __shfl_xor(m, off, 64);
            float s2 = __shfl_xor(s, off, 64);
            lse2_combine(m, s, m2, s2);
        }

        __shared__ float sm_m[4], sm_s[4];
        if (lane == 0) { sm_m[wid] = m; sm_s[wid] = s; }
        __syncthreads();
        if (tid == 0) {
            float M = sm_m[0], S = sm_s[0];
            lse2_combine(M, S, sm_m[1], sm_s[1]);
            lse2_combine(M, S, sm_m[2], sm_s[2]);
            lse2_combine(M, S, sm_m[3], sm_s[3]);
            ws[CE_OFF + row] = (M + log2f(S)) * LN2 - SCALE_F * target;
        }
    } else if (blk < CE_BLOCKS + CEN_BLOCKS) {
        // ---------------- center-hinge row ----------------
        const int row = blk - CE_BLOCKS;
        const int la = labels_a[row];
        const int ln = labels_n[row];

        float4 a  = ((const float4*)(anchor    + (size_t)row * D))[tid];
        float4 n  = ((const float4*)(negative  + (size_t)row * D))[tid];
        float4 ea = ((const float4*)(exemplars + (size_t)la  * D))[tid];
        float4 en = ((const float4*)(exemplars + (size_t)ln  * D))[tid];

        // s1=d_ref1(a,ea) s2=d_neg1(n,ea) s3=d_ref2(a,en) s4=d_neg2(n,en)
        float s1 = fabsf(a.x - ea.x + EPS_F) + fabsf(a.y - ea.y + EPS_F)
                 + fabsf(a.z - ea.z + EPS_F) + fabsf(a.w - ea.w + EPS_F);
        float s2 = fabsf(n.x - ea.x + EPS_F) + fabsf(n.y - ea.y + EPS_F)
                 + fabsf(n.z - ea.z + EPS_F) + fabsf(n.w - ea.w + EPS_F);
        float s3 = fabsf(a.x - en.x + EPS_F) + fabsf(a.y - en.y + EPS_F)
                 + fabsf(a.z - en.z + EPS_F) + fabsf(a.w - en.w + EPS_F);
        float s4 = fabsf(n.x - en.x + EPS_F) + fabsf(n.y - en.y + EPS_F)
                 + fabsf(n.z - en.z + EPS_F) + fabsf(n.w - en.w + EPS_F);

        #pragma unroll
        for (int off = 1; off < 64; off <<= 1) {
            s1 += __shfl_xor(s1, off, 64);
            s2 += __shfl_xor(s2, off, 64);
            s3 += __shfl_xor(s3, off, 64);
            s4 += __shfl_xor(s4, off, 64);
        }

        __shared__ float sm[4][4];
        if (lane == 0) { sm[wid][0] = s1; sm[wid][1] = s2; sm[wid][2] = s3; sm[wid][3] = s4; }
        __syncthreads();
        if (tid == 0) {
            float t1 = sm[0][0] + sm[1][0] + sm[2][0] + sm[3][0];
            float t2 = sm[0][1] + sm[1][1] + sm[2][1] + sm[3][1];
            float t3 = sm[0][2] + sm[1][2] + sm[2][2] + sm[3][2];
            float t4 = sm[0][3] + sm[1][3] + sm[2][3] + sm[3][3];
            ws[CEN_OFF + row] = fmaxf(t1 - t2, 0.0f) + fmaxf(t4 - t3, 0.0f);
        }
    } else {
        // ---------------- exemplar sum-of-squares chunk ----------------
        const int chunk = blk - (CE_BLOCKS + CEN_BLOCKS);
        const int n4 = C * D / 4;                 // 2,560,000 float4
        const float4* p = (const float4*)exemplars;
        float s = 0.0f;
        for (int i = chunk * 256 + tid; i < n4; i += SQ_BLOCKS * 256) {
            float4 v = p[i];
            s = fmaf(v.x, v.x, s); s = fmaf(v.y, v.y, s);
            s = fmaf(v.z, v.z, s); s = fmaf(v.w, v.w, s);
        }
        #pragma unroll
        for (int off = 1; off < 64; off <<= 1) s += __shfl_xor(s, off, 64);

        __shared__ float smq[4];
        if (lane == 0) smq[wid] = s;
        __syncthreads();
        if (tid == 0) ws[SQ_OFF + chunk] = smq[0] + smq[1] + smq[2] + smq[3];
    }
}

// ---------------------------------------------------------------------------
// Finalize — reduce all partials, write d_out[3].
// ---------------------------------------------------------------------------
__global__ __launch_bounds__(256) void finalize_kernel(const float* __restrict__ ws,
                                                       float* __restrict__ out) {
    const int tid = threadIdx.x;
    float ce = 0.0f, cen = 0.0f, sq = 0.0f;
    for (int i = tid; i < CE_BLOCKS; i += 256)  ce  += ws[CE_OFF  + i];
    for (int i = tid; i < B; i += 256)          cen += ws[CEN_OFF + i];
    for (int i = tid; i < SQ_BLOCKS; i += 256)  sq  += ws[SQ_OFF  + i];

    #pragma unroll
    for (int off = 1; off < 64; off <<= 1) {
        ce  += __shfl_xor(ce,  off, 64);
        cen += __shfl_xor(cen, off, 64);
        sq  += __shfl_xor(sq,  off, 64);
    }

    __shared__ float sm[4][3];
    const int wid = tid >> 6, lane = tid & 63;
    if (lane == 0) { sm[wid][0] = ce; sm[wid][1] = cen; sm[wid][2] = sq; }
    __syncthreads();
    if (tid == 0) {
        float CE  = (sm[0][0] + sm[1][0] + sm[2][0] + sm[3][0]) * (1.0f / (2.0f * B));
        float CEN =  sm[0][1] + sm[1][1] + sm[2][1] + sm[3][1];
        float SQ  =  sm[0][2] + sm[1][2] + sm[2][2] + sm[3][2];
        float total = (SQ == 0.0f) ? CE : CE + LAMBDA_F * CEN;
        out[0] = total;
        out[1] = CE;
        out[2] = CEN;
    }
}

extern "C" void kernel_launch(void* const* d_in, const int* in_sizes, int n_in,
                              void* d_out, int out_size, void* d_ws, size_t ws_size,
                              hipStream_t stream) {
    const float* anchor    = (const float*)d_in[0];
    const float* negative  = (const float*)d_in[1];
    const float* outputs   = (const float*)d_in[2];
    const int*   labels_a  = (const int*)d_in[3];
    const int*   labels_n  = (const int*)d_in[4];
    const float* exemplars = (const float*)d_in[5];
    float* out = (float*)d_out;
    float* ws  = (float*)d_ws;

    fused_kernel<<<TOTAL_BLOCKS, 256, 0, stream>>>(outputs, anchor, negative,
                                                   exemplars, labels_a, labels_n, ws);
    finalize_kernel<<<1, 256, 0, stream>>>(ws, out);
}